// Round 6
// baseline (452.169 us; speedup 1.0000x reference)
//
#include <hip/hip_runtime.h>

// Problem constants
#define B_   4
#define C_   256
#define L_   4096     // H*W = 64*64
#define NH_  4
#define D_   64       // head dim
#define G_   32       // groups
#define CPG_ 8        // channels per group

typedef __bf16 bf16x8 __attribute__((ext_vector_type(8)));
typedef float  f32x4  __attribute__((ext_vector_type(4)));

__device__ __forceinline__ ushort f2bf(float f) {
  union { float f; unsigned u; } c; c.f = f;
  unsigned u = c.u;
  return (ushort)((u + 0x7fffu + ((u >> 16) & 1u)) >> 16);   // RNE, finite values only
}
__device__ __forceinline__ float bf2f(ushort h) {
  union { unsigned u; float f; } c; c.u = ((unsigned)h) << 16; return c.f;
}
__device__ __forceinline__ unsigned fbits(float f) {
  union { float f; unsigned u; } c; c.f = f; return c.u;
}
__device__ __forceinline__ float fastexp2(float x) {
#if __has_builtin(__builtin_amdgcn_exp2f)
  return __builtin_amdgcn_exp2f(x);
#else
  return exp2f(x);
#endif
}

// ---------------------------------------------------------------------------
// 0) Weight convert (f32->bf16) + zero the GN stats accumulators.
// ---------------------------------------------------------------------------
__global__ __launch_bounds__(256) void cvt_kernel(const float* __restrict__ wq,
                                                  const float* __restrict__ wp,
                                                  ushort* __restrict__ oq,
                                                  ushort* __restrict__ op,
                                                  float* __restrict__ stats) {
  int t = blockIdx.x * 256 + threadIdx.x;     // 65536 threads, 4 elems each
  if (blockIdx.x == 0) stats[threadIdx.x] = 0.f;   // 256 floats
  const int NQ4 = (768 * 256) / 4;            // 49152
  float4 v;
  if (t < NQ4) {
    v = ((const float4*)wq)[t];
    ((ushort4*)oq)[t] = make_ushort4(f2bf(v.x), f2bf(v.y), f2bf(v.z), f2bf(v.w));
  } else {
    int i = t - NQ4;
    v = ((const float4*)wp)[i];
    ((ushort4*)op)[i] = make_ushort4(f2bf(v.x), f2bf(v.y), f2bf(v.z), f2bf(v.w));
  }
}

// ---------------------------------------------------------------------------
// 1a) GN stats: 1024 blocks = 128 (b,g) x 8 chunks; atomicAdd partial sums.
// ---------------------------------------------------------------------------
__global__ __launch_bounds__(256) void gn_stats(const float* __restrict__ x,
                                                float* __restrict__ stats) {
  int bg = blockIdx.x >> 3, chunk = blockIdx.x & 7;
  int b = bg >> 5, g = bg & 31;
  const float* xg = x + ((size_t)b * C_ + g * CPG_) * L_ + chunk * 512;
  int tid = threadIdx.x;

  float s = 0.f, ss = 0.f;
  for (int c = 0; c < CPG_; ++c) {
    float2 v = ((const float2*)(xg + (size_t)c * L_))[tid];
    s  += v.x + v.y;
    ss += v.x * v.x + v.y * v.y;
  }
  for (int off = 32; off; off >>= 1) { s += __shfl_xor(s, off); ss += __shfl_xor(ss, off); }
  __shared__ float red[8];
  int w = tid >> 6;
  if ((tid & 63) == 0) { red[w] = s; red[4 + w] = ss; }
  __syncthreads();
  if (tid == 0) {
    atomicAdd(&stats[bg * 2],     red[0] + red[1] + red[2] + red[3]);
    atomicAdd(&stats[bg * 2 + 1], red[4] + red[5] + red[6] + red[7]);
  }
}

// ---------------------------------------------------------------------------
// 1b) GN apply: x (B,C,L) f32 -> hT (B,L,C) bf16, transposed.  1024 blocks.
// ---------------------------------------------------------------------------
__global__ __launch_bounds__(256) void gn_apply(const float* __restrict__ x,
                                                const float* __restrict__ gw,
                                                const float* __restrict__ gb,
                                                const float* __restrict__ stats,
                                                ushort* __restrict__ hT) {
  int bg = blockIdx.x >> 3, chunk = blockIdx.x & 7;
  int b = bg >> 5, g = bg & 31;
  const float* xg = x + ((size_t)b * C_ + g * CPG_) * L_;
  int tid = threadIdx.x;

  const float inv_n = 1.0f / (CPG_ * L_);
  float mean = stats[bg * 2] * inv_n;
  float var  = stats[bg * 2 + 1] * inv_n - mean * mean;
  float rstd = rsqrtf(var + 1e-5f);

  float wv[CPG_], bv[CPG_];
  for (int c = 0; c < CPG_; ++c) { wv[c] = gw[g * CPG_ + c]; bv[c] = gb[g * CPG_ + c]; }

  for (int li = 0; li < 2; ++li) {
    int l = chunk * 512 + li * 256 + tid;
    union { ushort s[8]; uint4 u; } o;
    for (int c = 0; c < CPG_; ++c) {
      float v = xg[(size_t)c * L_ + l];
      o.s[c] = f2bf((v - mean) * rstd * wv[c] + bv[c]);
    }
    *(uint4*)(hT + ((size_t)b * L_ + l) * C_ + g * CPG_) = o.u;
  }
}

// ---------------------------------------------------------------------------
// 2) QKV GEMM (MFMA), 4 otiles x 2 ltiles per wave (64 o x 32 l).
//    q,k (b,h,L,d); v (b,h,d,L).  q PRE-SCALED by 0.125*log2(e).
// ---------------------------------------------------------------------------
__global__ __launch_bounds__(256) void qkv_kernel(const ushort* __restrict__ hT,
                                                  const ushort* __restrict__ w,
                                                  const float* __restrict__ bias,
                                                  ushort* __restrict__ q,
                                                  ushort* __restrict__ k,
                                                  ushort* __restrict__ v) {
  int wid  = blockIdx.x * 4 + (threadIdx.x >> 6);   // 6144 waves
  int lane = threadIdx.x & 63;
  int quad = lane >> 4, col = lane & 15;
  int ot   = wid % 12;            // 64 o-channels
  int rest = wid / 12;
  int lt   = rest & 127;          // 32 l
  int b    = rest >> 7;
  int o0 = ot * 64, l0 = lt * 32;

  const ushort* abase = w  + (size_t)(o0 + col) * C_ + quad * 8;
  const ushort* bbase = hT + ((size_t)b * L_ + l0 + col) * C_ + quad * 8;

  f32x4 acc[4][2];
  for (int i = 0; i < 4; ++i) for (int j = 0; j < 2; ++j)
    acc[i][j] = (f32x4){0.f, 0.f, 0.f, 0.f};

#pragma unroll
  for (int k0 = 0; k0 < C_; k0 += 32) {
    bf16x8 a[4], bb[2];
#pragma unroll
    for (int i = 0; i < 4; ++i) a[i]  = *(const bf16x8*)(abase + (size_t)(i * 16) * C_ + k0);
#pragma unroll
    for (int j = 0; j < 2; ++j) bb[j] = *(const bf16x8*)(bbase + (size_t)(j * 16) * C_ + k0);
#pragma unroll
    for (int i = 0; i < 4; ++i)
#pragma unroll
      for (int j = 0; j < 2; ++j)
        acc[i][j] = __builtin_amdgcn_mfma_f32_16x16x32_bf16(a[i], bb[j], acc[i][j], 0, 0, 0);
  }

  int third = o0 >> 8;                       // wave-uniform (o0 is 64-aligned)
  int hh    = (o0 & 255) >> 6;               // wave-uniform
  float scale = (third == 0) ? 0.180336880111120f : 1.0f;  // 0.125*log2(e) on q
#pragma unroll
  for (int i = 0; i < 4; ++i) {
    int oo = o0 + i * 16 + quad * 4;
    int dd = i * 16 + quad * 4;
#pragma unroll
    for (int j = 0; j < 2; ++j) {
      int l = l0 + j * 16 + col;
      ushort pk[4];
      for (int r = 0; r < 4; ++r) pk[r] = f2bf((acc[i][j][r] + bias[oo + r]) * scale);
      if (third < 2) {
        ushort* dst = (third ? k : q) + (((size_t)(b * NH_ + hh) * L_ + l) * D_ + dd);
        *(ushort4*)dst = make_ushort4(pk[0], pk[1], pk[2], pk[3]);
      } else {
        for (int r = 0; r < 4; ++r)
          v[((size_t)(b * NH_ + hh) * D_ + dd + r) * L_ + l] = pk[r];
      }
    }
  }
}

// ---------------------------------------------------------------------------
// 3) Flash attention (MFMA) v9: LDS-lean + wave-diverse.
//    Model (R1/R4/R5): per-CU MFMA 33us || VALU 35us || LDS 31us, sum ==
//    wall time => zero overlap at 2 waves/SIMD.  Fixes:
//      - V NEVER goes through LDS: v8's permuted-LDS read pattern equals a
//        direct global read v[(t*16+col)*L + kt + h*32 + quad*4] (+16)
//        (verified element-wise) -- V is L2-resident via XCD swizzle.
//        Kills half the LDS pipe (reads AND staging writes).
//      - K tile UNPADDED [64][64] with XOR swizzle lds[row][inn^(row&7)]
//        on write and read -> conflict-free b128 both sides, 16 KB/block.
//      - 32 q-rows/wave (4096 waves), 128-thr/2-wave blocks, grid 2048
//        (split2 x bh16 x qblk64) -> 6+ independent blocks/CU, 3 waves/SIMD
//        (__launch_bounds__(128,3), VGPR~155 under the 170 cap; R3 spill
//        guard: WRITE_SIZE must stay ~16.9MB).
//      - per-h JIT V loads (16 VGPR), exp(h) covers L2 latency.
// ---------------------------------------------------------------------------
__global__ __launch_bounds__(128, 3) void attn_kernel(const ushort* __restrict__ q,
                                                      const ushort* __restrict__ k,
                                                      const ushort* __restrict__ v,
                                                      ushort* __restrict__ p0,
                                                      ushort* __restrict__ p1,
                                                      float* __restrict__ psumbuf) {
  __shared__ __align__(16) ushort k_lds[2][64][64];   // K tiles, XOR-swizzled

  int tid   = threadIdx.x;
  int w     = tid >> 6, lane = tid & 63;
  int quad  = lane >> 4, col = lane & 15;
  int bid   = (int)blockIdx.x;
  bid = (bid & 7) * 256 + (bid >> 3);    // XCD-contiguous work ids (2048 % 8 == 0)
  int split = bid >> 10;                 // 0 or 1
  int bh    = (bid >> 6) & 15;
  int qblk  = bid & 63;

  const ushort* qp = q + (size_t)bh * L_ * D_;
  const ushort* kp = k + (size_t)bh * L_ * D_;
  const ushort* vp = v + (size_t)bh * D_ * L_;

  int qrow0 = qblk * 64 + w * 32;        // this wave's 32 q-rows
  bf16x8 bq[2][2];                       // [frag][c]
#pragma unroll
  for (int f = 0; f < 2; ++f)
#pragma unroll
    for (int c = 0; c < 2; ++c)
      bq[f][c] = *(const bf16x8*)(qp + (size_t)(qrow0 + f * 16 + col) * D_ + c * 32 + quad * 8);

  f32x4 oacc[2][4];
#pragma unroll
  for (int f = 0; f < 2; ++f)
    for (int t = 0; t < 4; ++t) oacc[f][t] = (f32x4){0.f, 0.f, 0.f, 0.f};
  float psum[2] = {0.f, 0.f};
  const f32x4 Z = (f32x4){0.f, 0.f, 0.f, 0.f};

  // K staging: 128 thr x 4 uint4 = 8 KB tile; XOR-swizzled LDS writes.
  int wrow = tid >> 3;                               // 0..15
  int winn = ((tid & 7) ^ (wrow & 7)) * 8;           // swizzled inner (ushorts)
  // K frag read swizzle (row&7 == col&7 for all our rows):
  int sw0 = ((quad)     ^ (col & 7)) * 8;
  int sw4 = ((quad + 4) ^ (col & 7)) * 8;

  int kt0 = split * (L_ / 2), kt_end = kt0 + L_ / 2;

#define STAGE_K(NB, A0, A1, A2, A3) { \
    *(uint4*)&k_lds[NB][wrow][winn]      = A0; \
    *(uint4*)&k_lds[NB][16 + wrow][winn] = A1; \
    *(uint4*)&k_lds[NB][32 + wrow][winn] = A2; \
    *(uint4*)&k_lds[NB][48 + wrow][winn] = A3; \
  }

  // prologue: stage tile kt0 into buffer 0
  {
    const uint4* ksrc = (const uint4*)(kp + (size_t)kt0 * D_);   // 8 KB contiguous
    uint4 a0 = ksrc[tid], a1 = ksrc[tid + 128], a2 = ksrc[tid + 256], a3 = ksrc[tid + 384];
    STAGE_K(0, a0, a1, a2, a3);
  }
  __syncthreads();

  int cur = 0;
  for (int kt = kt0; kt < kt_end; kt += 64) {
    bool has_next = (kt + 64) < kt_end;   // block-uniform

    // ---- issue next K tile's global loads early (T14) ----
    uint4 nk0, nk1, nk2, nk3;
    if (has_next) {
      const uint4* ksrc = (const uint4*)(kp + (size_t)(kt + 64) * D_);
      nk0 = ksrc[tid]; nk1 = ksrc[tid + 128]; nk2 = ksrc[tid + 256]; nk3 = ksrc[tid + 384];
    }

    // ---- QK^T for BOTH 32-kpos halves (16 indep MFMAs) ----
    f32x4 s[2][2][2];   // [h][f][{rows col, rows 16+col}]
#pragma unroll
    for (int h = 0; h < 2; ++h) {
      bf16x8 a00 = *(const bf16x8*)&k_lds[cur][h * 32 + col][sw0];
      bf16x8 a01 = *(const bf16x8*)&k_lds[cur][h * 32 + col][sw4];
      bf16x8 a10 = *(const bf16x8*)&k_lds[cur][h * 32 + 16 + col][sw0];
      bf16x8 a11 = *(const bf16x8*)&k_lds[cur][h * 32 + 16 + col][sw4];
#pragma unroll
      for (int f = 0; f < 2; ++f) {
        s[h][f][0] = __builtin_amdgcn_mfma_f32_16x16x32_bf16(a00, bq[f][0], Z, 0, 0, 0);
        s[h][f][1] = __builtin_amdgcn_mfma_f32_16x16x32_bf16(a10, bq[f][0], Z, 0, 0, 0);
        s[h][f][0] = __builtin_amdgcn_mfma_f32_16x16x32_bf16(a01, bq[f][1], s[h][f][0], 0, 0, 0);
        s[h][f][1] = __builtin_amdgcn_mfma_f32_16x16x32_bf16(a11, bq[f][1], s[h][f][1], 0, 0, 0);
      }
    }

    // ---- per half: JIT V global loads + exp/pack (VALU) + PV (MFMA) ----
#pragma unroll
    for (int h = 0; h < 2; ++h) {
      // V A-frags DIRECT from global (L2-hit; pattern == v8's permuted LDS)
      uint2 vf[4][2];
#pragma unroll
      for (int t = 0; t < 4; ++t) {
        const ushort* vb = vp + (size_t)(t * 16 + col) * L_ + kt + h * 32 + quad * 4;
        vf[t][0] = *(const uint2*)vb;
        vf[t][1] = *(const uint2*)(vb + 16);
      }

      bf16x8 pb[2];
#pragma unroll
      for (int f = 0; f < 2; ++f) {
        float pe0[4], pe1[4];
#pragma unroll
        for (int r = 0; r < 4; ++r) {
          pe0[r] = fastexp2(s[h][f][0][r]);
          pe1[r] = fastexp2(s[h][f][1][r]);
        }
        psum[f] += ((pe0[0] + pe0[1]) + (pe0[2] + pe0[3])) +
                   ((pe1[0] + pe1[1]) + (pe1[2] + pe1[3]));
        // B-frag IS our own values under the kpos permutation.
        union { unsigned u[4]; bf16x8 v8; } pc;
        pc.u[0] = __builtin_amdgcn_perm(fbits(pe0[1]), fbits(pe0[0]), 0x07060302u);
        pc.u[1] = __builtin_amdgcn_perm(fbits(pe0[3]), fbits(pe0[2]), 0x07060302u);
        pc.u[2] = __builtin_amdgcn_perm(fbits(pe1[1]), fbits(pe1[0]), 0x07060302u);
        pc.u[3] = __builtin_amdgcn_perm(fbits(pe1[3]), fbits(pe1[2]), 0x07060302u);
        pb[f] = pc.v8;
      }
#pragma unroll
      for (int t = 0; t < 4; ++t) {
        union { uint2 u2[2]; bf16x8 v8; } vc;
        vc.u2[0] = vf[t][0];
        vc.u2[1] = vf[t][1];
#pragma unroll
        for (int f = 0; f < 2; ++f)
          oacc[f][t] = __builtin_amdgcn_mfma_f32_16x16x32_bf16(vc.v8, pb[f], oacc[f][t], 0, 0, 0);
      }
    }

    if (has_next) {
      int nb = cur ^ 1;
      STAGE_K(nb, nk0, nk1, nk2, nk3);
      __syncthreads();
      cur = nb;
    }
  }
#undef STAGE_K

  ushort* po = split ? p1 : p0;
#pragma unroll
  for (int f = 0; f < 2; ++f) {
    psum[f] += __shfl_xor(psum[f], 16);
    psum[f] += __shfl_xor(psum[f], 32);
    for (int t = 0; t < 4; ++t) {
      ushort ok[4];
      for (int r = 0; r < 4; ++r) ok[r] = f2bf(oacc[f][t][r]);   // unnormalized
      ushort* dst = po + ((size_t)bh * L_ + qrow0 + f * 16 + col) * D_ + t * 16 + quad * 4;
      *(ushort4*)dst = make_ushort4(ok[0], ok[1], ok[2], ok[3]);
    }
    if (quad == 0)
      psumbuf[split * (16 * L_) + bh * L_ + qrow0 + f * 16 + col] = psum[f];
  }
}

// ---------------------------------------------------------------------------
// 3b) Combine: oat = (U0 + U1) / (P0 + P1), in-place over p0.
// ---------------------------------------------------------------------------
__global__ __launch_bounds__(256) void comb_kernel(ushort* __restrict__ p0,      // in/out (oat)
                                                   const ushort* __restrict__ p1,
                                                   const float* __restrict__ ps) {
  int idx = blockIdx.x * 256 + threadIdx.x;    // 1,048,576 = 16*4096*16
  int row = idx >> 4;                          // bh*4096 + qrow
  float inv = 1.0f / (ps[row] + ps[16 * L_ + row]);
  ushort4 a = ((const ushort4*)p0)[idx];
  ushort4 b = ((const ushort4*)p1)[idx];
  ((ushort4*)p0)[idx] = make_ushort4(
      f2bf((bf2f(a.x) + bf2f(b.x)) * inv),
      f2bf((bf2f(a.y) + bf2f(b.y)) * inv),
      f2bf((bf2f(a.z) + bf2f(b.z)) * inv),
      f2bf((bf2f(a.w) + bf2f(b.w)) * inv));
}

// ---------------------------------------------------------------------------
// 4) Proj GEMM + residual (MFMA), 2 ltiles x 2 octiles per wave.
//    x f32; OUT IS F32.
// ---------------------------------------------------------------------------
__global__ __launch_bounds__(256) void proj_kernel(const ushort* __restrict__ oin,
                                                   const ushort* __restrict__ pw,
                                                   const float* __restrict__ pb,
                                                   const float* __restrict__ x,
                                                   float* __restrict__ out) {
  int wid  = blockIdx.x * 4 + (threadIdx.x >> 6);   // 4096 waves
  int lane = threadIdx.x & 63;
  int quad = lane >> 4, col = lane & 15;
  int oct  = wid & 7;             // 32 oc
  int rest = wid >> 3;
  int lt   = rest & 127;          // 32 l
  int b    = rest >> 7;
  int l0 = lt * 32, oc0 = oct * 32;

  f32x4 acc[2][2];
  for (int i = 0; i < 2; ++i) for (int j = 0; j < 2; ++j)
    acc[i][j] = (f32x4){0.f, 0.f, 0.f, 0.f};

#pragma unroll
  for (int k0 = 0; k0 < C_; k0 += 32) {
    int hh = k0 >> 6, dk = k0 & 63;
    bf16x8 a[2], bb[2];
#pragma unroll
    for (int i = 0; i < 2; ++i)
      a[i] = *(const bf16x8*)(oin + ((size_t)(b * NH_ + hh) * L_ + l0 + i * 16 + col) * D_ + dk + quad * 8);
#pragma unroll
    for (int j = 0; j < 2; ++j)
      bb[j] = *(const bf16x8*)(pw + (size_t)(oc0 + j * 16 + col) * C_ + k0 + quad * 8);
#pragma unroll
    for (int i = 0; i < 2; ++i)
#pragma unroll
      for (int j = 0; j < 2; ++j)
        acc[i][j] = __builtin_amdgcn_mfma_f32_16x16x32_bf16(a[i], bb[j], acc[i][j], 0, 0, 0);
  }

#pragma unroll
  for (int j = 0; j < 2; ++j) {
    int oc = oc0 + j * 16 + col;
    float bias = pb[oc];
#pragma unroll
    for (int i = 0; i < 2; ++i) {
      int l = l0 + i * 16 + quad * 4;
      size_t off = ((size_t)b * C_ + oc) * L_ + l;
      float4 xv = *(const float4*)(x + off);
      float4 ov = make_float4(acc[i][j][0] + bias + xv.x,
                              acc[i][j][1] + bias + xv.y,
                              acc[i][j][2] + bias + xv.z,
                              acc[i][j][3] + bias + xv.w);
      *(float4*)(out + off) = ov;
    }
  }
}

// ---------------------------------------------------------------------------
extern "C" void kernel_launch(void* const* d_in, const int* in_sizes, int n_in,
                              void* d_out, int out_size, void* d_ws, size_t ws_size,
                              hipStream_t stream) {
  const float* x      = (const float*)d_in[0];
  const float* gn_w   = (const float*)d_in[1];
  const float* gn_b   = (const float*)d_in[2];
  const float* qkv_w  = (const float*)d_in[3];
  const float* qkv_b  = (const float*)d_in[4];
  const float* proj_w = (const float*)d_in[5];
  const float* proj_b = (const float*)d_in[6];
  float* out = (float*)d_out;     // OUTPUT IS F32

  const size_t TEN = (size_t)B_ * C_ * L_;   // 4,194,304 elements
  // ws: q | k | v | oat | wq | wp | stats (34.1 MB + 1 KB)
  // d_out (16.8 MB): [0,8.4M) hT bf16 (dead after qkv) -> psum f32 (512 KB);
  //                  [8.4M,16.8M) partial-1 (bf16).
  ushort* ws  = (ushort*)d_ws;
  ushort* q   = ws;                 // (B, nh, L, d) bf16 (pre-scaled)
  ushort* k   = ws + TEN;           // (B, nh, L, d) bf16
  ushort* v   = ws + 2 * TEN;       // (B, nh, d, L) bf16
  ushort* oat = ws + 3 * TEN;       // (B, nh, L, d) bf16 = partial-0, then O
  ushort* wq  = ws + 4 * TEN;       // (768,256) bf16
  ushort* wp  = wq + 768 * 256;     // (256,256) bf16
  float*  stats = (float*)(wp + 256 * 256);   // 256 f32 (zeroed by cvt)
  ushort* hT  = (ushort*)d_out;     // (B, L, C) bf16 staging inside d_out
  ushort* p1  = (ushort*)d_out + TEN;   // partial-1 (bf16)
  float*  psb = (float*)d_out;          // psum[2][16][4096] f32 over dead hT

  cvt_kernel <<<256,       256, 0, stream>>>(qkv_w, proj_w, wq, wp, stats);
  gn_stats   <<<1024,      256, 0, stream>>>(x, stats);
  gn_apply   <<<1024,      256, 0, stream>>>(x, gn_w, gn_b, stats, hT);
  qkv_kernel <<<6144 / 4,  256, 0, stream>>>(hT, wq, qkv_b, q, k, v);
  attn_kernel<<<2048,      128, 0, stream>>>(q, k, v, oat, p1, psb);
  comb_kernel<<<4096,      256, 0, stream>>>(oat, p1, psb);
  proj_kernel<<<4096 / 4,  256, 0, stream>>>(oat, wp, proj_b, x, out);
}

// Round 7
// 256.812 us; speedup vs baseline: 1.7607x; 1.7607x over previous
//
#include <hip/hip_runtime.h>

// Problem constants
#define B_   4
#define C_   256
#define L_   4096     // H*W = 64*64
#define NH_  4
#define D_   64       // head dim
#define G_   32       // groups
#define CPG_ 8        // channels per group

typedef __bf16 bf16x8 __attribute__((ext_vector_type(8)));
typedef float  f32x4  __attribute__((ext_vector_type(4)));

__device__ __forceinline__ ushort f2bf(float f) {
  union { float f; unsigned u; } c; c.f = f;
  unsigned u = c.u;
  return (ushort)((u + 0x7fffu + ((u >> 16) & 1u)) >> 16);   // RNE, finite values only
}
__device__ __forceinline__ float bf2f(ushort h) {
  union { unsigned u; float f; } c; c.u = ((unsigned)h) << 16; return c.f;
}
__device__ __forceinline__ unsigned fbits(float f) {
  union { float f; unsigned u; } c; c.f = f; return c.u;
}
__device__ __forceinline__ float fastexp2(float x) {
#if __has_builtin(__builtin_amdgcn_exp2f)
  return __builtin_amdgcn_exp2f(x);
#else
  return exp2f(x);
#endif
}

// ---------------------------------------------------------------------------
// 0) Weight convert (f32->bf16) + zero the GN stats accumulators.
// ---------------------------------------------------------------------------
__global__ __launch_bounds__(256) void cvt_kernel(const float* __restrict__ wq,
                                                  const float* __restrict__ wp,
                                                  ushort* __restrict__ oq,
                                                  ushort* __restrict__ op,
                                                  float* __restrict__ stats) {
  int t = blockIdx.x * 256 + threadIdx.x;     // 65536 threads, 4 elems each
  if (blockIdx.x == 0) stats[threadIdx.x] = 0.f;   // 256 floats
  const int NQ4 = (768 * 256) / 4;            // 49152
  float4 v;
  if (t < NQ4) {
    v = ((const float4*)wq)[t];
    ((ushort4*)oq)[t] = make_ushort4(f2bf(v.x), f2bf(v.y), f2bf(v.z), f2bf(v.w));
  } else {
    int i = t - NQ4;
    v = ((const float4*)wp)[i];
    ((ushort4*)op)[i] = make_ushort4(f2bf(v.x), f2bf(v.y), f2bf(v.z), f2bf(v.w));
  }
}

// ---------------------------------------------------------------------------
// 1a) GN stats: 1024 blocks = 128 (b,g) x 8 chunks; atomicAdd partial sums.
// ---------------------------------------------------------------------------
__global__ __launch_bounds__(256) void gn_stats(const float* __restrict__ x,
                                                float* __restrict__ stats) {
  int bg = blockIdx.x >> 3, chunk = blockIdx.x & 7;
  int b = bg >> 5, g = bg & 31;
  const float* xg = x + ((size_t)b * C_ + g * CPG_) * L_ + chunk * 512;
  int tid = threadIdx.x;

  float s = 0.f, ss = 0.f;
  for (int c = 0; c < CPG_; ++c) {
    float2 v = ((const float2*)(xg + (size_t)c * L_))[tid];
    s  += v.x + v.y;
    ss += v.x * v.x + v.y * v.y;
  }
  for (int off = 32; off; off >>= 1) { s += __shfl_xor(s, off); ss += __shfl_xor(ss, off); }
  __shared__ float red[8];
  int w = tid >> 6;
  if ((tid & 63) == 0) { red[w] = s; red[4 + w] = ss; }
  __syncthreads();
  if (tid == 0) {
    atomicAdd(&stats[bg * 2],     red[0] + red[1] + red[2] + red[3]);
    atomicAdd(&stats[bg * 2 + 1], red[4] + red[5] + red[6] + red[7]);
  }
}

// ---------------------------------------------------------------------------
// 1b) GN apply: x (B,C,L) f32 -> hT (B,L,C) bf16, transposed.  1024 blocks.
// ---------------------------------------------------------------------------
__global__ __launch_bounds__(256) void gn_apply(const float* __restrict__ x,
                                                const float* __restrict__ gw,
                                                const float* __restrict__ gb,
                                                const float* __restrict__ stats,
                                                ushort* __restrict__ hT) {
  int bg = blockIdx.x >> 3, chunk = blockIdx.x & 7;
  int b = bg >> 5, g = bg & 31;
  const float* xg = x + ((size_t)b * C_ + g * CPG_) * L_;
  int tid = threadIdx.x;

  const float inv_n = 1.0f / (CPG_ * L_);
  float mean = stats[bg * 2] * inv_n;
  float var  = stats[bg * 2 + 1] * inv_n - mean * mean;
  float rstd = rsqrtf(var + 1e-5f);

  float wv[CPG_], bv[CPG_];
  for (int c = 0; c < CPG_; ++c) { wv[c] = gw[g * CPG_ + c]; bv[c] = gb[g * CPG_ + c]; }

  for (int li = 0; li < 2; ++li) {
    int l = chunk * 512 + li * 256 + tid;
    union { ushort s[8]; uint4 u; } o;
    for (int c = 0; c < CPG_; ++c) {
      float v = xg[(size_t)c * L_ + l];
      o.s[c] = f2bf((v - mean) * rstd * wv[c] + bv[c]);
    }
    *(uint4*)(hT + ((size_t)b * L_ + l) * C_ + g * CPG_) = o.u;
  }
}

// ---------------------------------------------------------------------------
// 2) QKV GEMM (MFMA), 4 otiles x 2 ltiles per wave (64 o x 32 l).
//    q,k (b,h,L,d); v (b,h,d,L).  q PRE-SCALED by 0.125*log2(e).
// ---------------------------------------------------------------------------
__global__ __launch_bounds__(256) void qkv_kernel(const ushort* __restrict__ hT,
                                                  const ushort* __restrict__ w,
                                                  const float* __restrict__ bias,
                                                  ushort* __restrict__ q,
                                                  ushort* __restrict__ k,
                                                  ushort* __restrict__ v) {
  int wid  = blockIdx.x * 4 + (threadIdx.x >> 6);   // 6144 waves
  int lane = threadIdx.x & 63;
  int quad = lane >> 4, col = lane & 15;
  int ot   = wid % 12;            // 64 o-channels
  int rest = wid / 12;
  int lt   = rest & 127;          // 32 l
  int b    = rest >> 7;
  int o0 = ot * 64, l0 = lt * 32;

  const ushort* abase = w  + (size_t)(o0 + col) * C_ + quad * 8;
  const ushort* bbase = hT + ((size_t)b * L_ + l0 + col) * C_ + quad * 8;

  f32x4 acc[4][2];
  for (int i = 0; i < 4; ++i) for (int j = 0; j < 2; ++j)
    acc[i][j] = (f32x4){0.f, 0.f, 0.f, 0.f};

#pragma unroll
  for (int k0 = 0; k0 < C_; k0 += 32) {
    bf16x8 a[4], bb[2];
#pragma unroll
    for (int i = 0; i < 4; ++i) a[i]  = *(const bf16x8*)(abase + (size_t)(i * 16) * C_ + k0);
#pragma unroll
    for (int j = 0; j < 2; ++j) bb[j] = *(const bf16x8*)(bbase + (size_t)(j * 16) * C_ + k0);
#pragma unroll
    for (int i = 0; i < 4; ++i)
#pragma unroll
      for (int j = 0; j < 2; ++j)
        acc[i][j] = __builtin_amdgcn_mfma_f32_16x16x32_bf16(a[i], bb[j], acc[i][j], 0, 0, 0);
  }

  int third = o0 >> 8;                       // wave-uniform (o0 is 64-aligned)
  int hh    = (o0 & 255) >> 6;               // wave-uniform
  float scale = (third == 0) ? 0.180336880111120f : 1.0f;  // 0.125*log2(e) on q
#pragma unroll
  for (int i = 0; i < 4; ++i) {
    int oo = o0 + i * 16 + quad * 4;
    int dd = i * 16 + quad * 4;
#pragma unroll
    for (int j = 0; j < 2; ++j) {
      int l = l0 + j * 16 + col;
      ushort pk[4];
      for (int r = 0; r < 4; ++r) pk[r] = f2bf((acc[i][j][r] + bias[oo + r]) * scale);
      if (third < 2) {
        ushort* dst = (third ? k : q) + (((size_t)(b * NH_ + hh) * L_ + l) * D_ + dd);
        *(ushort4*)dst = make_ushort4(pk[0], pk[1], pk[2], pk[3]);
      } else {
        for (int r = 0; r < 4; ++r)
          v[((size_t)(b * NH_ + hh) * D_ + dd + r) * L_ + l] = pk[r];
      }
    }
  }
}

// ---------------------------------------------------------------------------
// 3) Flash attention (MFMA) v12 = v7 (R4 best, 77.5us) + K-direct-to-REGISTER
//    fragments prefetched ONE TILE AHEAD (ping-pong kfA/kfB, static indices).
//    R6 lesson: direct-global is fine ONLY with tile-ahead prefetch; its JIT
//    V loads exposed full memory latency (317us).  K's QK A-frag pattern from
//    global k (L,d) is per-lane 16B contiguous (same coalescing as the old
//    staging load) and the 8KB tile is L1-resident for the block's 4 waves.
//    Removes per tile: 2 K stage-stores + 8 K ds_read_b128 + K's barrier
//    dependency -> LDS pipe ~halved, tile critical path loses the K-wait.
//    V keeps the proven v7 LDS double-buffer (its transpose needs LDS).
//    64 q-rows/wave, split=2, grid 512, 256 thr, __launch_bounds__(256,2)
//    (R3 lesson: 256-VGPR budget; spill guard = WRITE_SIZE ~16.9MB).
// ---------------------------------------------------------------------------
__global__ __launch_bounds__(256, 2) void attn_kernel(const ushort* __restrict__ q,
                                                      const ushort* __restrict__ k,
                                                      const ushort* __restrict__ v,
                                                      ushort* __restrict__ p0,
                                                      ushort* __restrict__ p1,
                                                      float* __restrict__ psumbuf) {
  __shared__ __align__(16) ushort v_lds[2][64][72];   // V^T tiles (permuted), +8 pad

  int tid   = threadIdx.x;
  int w     = tid >> 6, lane = tid & 63;
  int quad  = lane >> 4, col = lane & 15;
  int bid   = (int)blockIdx.x;
  bid = (bid & 7) * 64 + (bid >> 3);     // XCD-contiguous work ids (512 % 8 == 0)
  int split = bid >> 8;                  // 0 or 1
  int bh    = (bid >> 4) & 15;
  int qblk  = bid & 15;

  const ushort* qp = q + (size_t)bh * L_ * D_;
  const ushort* kp = k + (size_t)bh * L_ * D_;
  const ushort* vp = v + (size_t)bh * D_ * L_;

  int qrow0 = qblk * 256 + w * 64;       // this wave's 64 q-rows
  bf16x8 bq[4][2];                       // [frag][c]
#pragma unroll
  for (int f = 0; f < 4; ++f)
#pragma unroll
    for (int c = 0; c < 2; ++c)
      bq[f][c] = *(const bf16x8*)(qp + (size_t)(qrow0 + f * 16 + col) * D_ + c * 32 + quad * 8);

  f32x4 oacc[4][4];
#pragma unroll
  for (int f = 0; f < 4; ++f)
    for (int t = 0; t < 4; ++t) oacc[f][t] = (f32x4){0.f, 0.f, 0.f, 0.f};
  float psum[4] = {0.f, 0.f, 0.f, 0.f};
  const f32x4 Z = (f32x4){0.f, 0.f, 0.f, 0.f};

  int vrow = tid >> 2, vchunk = tid & 3;
  int vwoff = (vchunk >> 1) * 32 + (vchunk & 1) * 4;   // permuted V store base
  int kt0 = split * (L_ / 2);

  bf16x8 kfA[2][2][2], kfB[2][2][2];     // K-frag ping-pong [h][rowhalf][c]
  uint4 gv0, gv1;                        // V staging regs

  // K frags DIRECT from global (rows = h*32 + {col, 16+col}; 16B/lane):
#define LOAD_KF(KF, KT) { \
    _Pragma("unroll") \
    for (int h = 0; h < 2; ++h) { \
      const ushort* kr0_ = kp + (size_t)((KT) + h * 32 + col) * D_ + quad * 8; \
      const ushort* kr1_ = kp + (size_t)((KT) + h * 32 + 16 + col) * D_ + quad * 8; \
      KF[h][0][0] = *(const bf16x8*)kr0_; \
      KF[h][0][1] = *(const bf16x8*)(kr0_ + 32); \
      KF[h][1][0] = *(const bf16x8*)kr1_; \
      KF[h][1][1] = *(const bf16x8*)(kr1_ + 32); \
    } \
  }

#define ISSUE_V(KT) { \
    const uint4* vsrc_ = (const uint4*)(vp + (size_t)vrow * L_ + (KT)); \
    gv0 = vsrc_[vchunk * 2]; \
    gv1 = vsrc_[vchunk * 2 + 1]; \
  }

#define STAGE_V(NB) { \
    ushort* vb_ = &v_lds[NB][vrow][vwoff]; \
    *(uint2*)(vb_ + 0)  = make_uint2(gv0.x, gv0.y); \
    *(uint2*)(vb_ + 8)  = make_uint2(gv0.z, gv0.w); \
    *(uint2*)(vb_ + 16) = make_uint2(gv1.x, gv1.y); \
    *(uint2*)(vb_ + 24) = make_uint2(gv1.z, gv1.w); \
  }

#define QK_T(KF, S) { \
    _Pragma("unroll") \
    for (int h = 0; h < 2; ++h) \
      _Pragma("unroll") \
      for (int f = 0; f < 4; ++f) { \
        S[h][f][0] = __builtin_amdgcn_mfma_f32_16x16x32_bf16(KF[h][0][0], bq[f][0], Z, 0, 0, 0); \
        S[h][f][1] = __builtin_amdgcn_mfma_f32_16x16x32_bf16(KF[h][1][0], bq[f][0], Z, 0, 0, 0); \
        S[h][f][0] = __builtin_amdgcn_mfma_f32_16x16x32_bf16(KF[h][0][1], bq[f][1], S[h][f][0], 0, 0, 0); \
        S[h][f][1] = __builtin_amdgcn_mfma_f32_16x16x32_bf16(KF[h][1][1], bq[f][1], S[h][f][1], 0, 0, 0); \
      } \
  }

#define SOFT_PV(S) { \
    _Pragma("unroll") \
    for (int h = 0; h < 2; ++h) { \
      bf16x8 pb[4]; \
      _Pragma("unroll") \
      for (int f = 0; f < 4; ++f) { \
        float pe0[4], pe1[4]; \
        _Pragma("unroll") \
        for (int r = 0; r < 4; ++r) { \
          pe0[r] = fastexp2(S[h][f][0][r]); \
          pe1[r] = fastexp2(S[h][f][1][r]); \
        } \
        psum[f] += ((pe0[0] + pe0[1]) + (pe0[2] + pe0[3])) + \
                   ((pe1[0] + pe1[1]) + (pe1[2] + pe1[3])); \
        union { unsigned u[4]; bf16x8 v8; } pc; \
        pc.u[0] = __builtin_amdgcn_perm(fbits(pe0[1]), fbits(pe0[0]), 0x07060302u); \
        pc.u[1] = __builtin_amdgcn_perm(fbits(pe0[3]), fbits(pe0[2]), 0x07060302u); \
        pc.u[2] = __builtin_amdgcn_perm(fbits(pe1[1]), fbits(pe1[0]), 0x07060302u); \
        pc.u[3] = __builtin_amdgcn_perm(fbits(pe1[3]), fbits(pe1[2]), 0x07060302u); \
        pb[f] = pc.v8; \
      } \
      _Pragma("unroll") \
      for (int t = 0; t < 4; ++t) { \
        bf16x8 av = *(const bf16x8*)&v_lds[cur][t * 16 + col][h * 32 + quad * 8]; \
        _Pragma("unroll") \
        for (int f = 0; f < 4; ++f) \
          oacc[f][t] = __builtin_amdgcn_mfma_f32_16x16x32_bf16(av, pb[f], oacc[f][t], 0, 0, 0); \
      } \
    } \
  }

  // BODY(tile at KT using KFC): prefetch K(KT+64)->KFN + issue V(KT+64);
  // QK(KT); exp/PV(KT); stage V(KT+64); barrier.
#define BODY(KFC, KFN, KT, HASNEXT) { \
    if (HASNEXT) { ISSUE_V((KT) + 64); LOAD_KF(KFN, (KT) + 64); } \
    f32x4 s[2][4][2]; \
    QK_T(KFC, s); \
    SOFT_PV(s); \
    if (HASNEXT) { int nb_ = cur ^ 1; STAGE_V(nb_); __syncthreads(); cur = nb_; } \
  }

  // ---- prologue: K frags tile0 -> kfA; V tile0 -> buf0 ----
  LOAD_KF(kfA, kt0);
  ISSUE_V(kt0);
  STAGE_V(0);
  __syncthreads();
  int cur = 0;

  // ---- tiles 0..29 (15 pairs) ----
  for (int j = 0; j < 15; ++j) {
    int t0 = kt0 + (2 * j) * 64;
    BODY(kfA, kfB, t0, true);        // even tile
    BODY(kfB, kfA, t0 + 64, true);   // odd tile
  }
  // ---- tile 30 (prefetch 31), tile 31 (no prefetch) ----
  BODY(kfA, kfB, kt0 + 30 * 64, true);
  BODY(kfB, kfA, kt0 + 31 * 64, false);

#undef BODY
#undef SOFT_PV
#undef QK_T
#undef STAGE_V
#undef ISSUE_V
#undef LOAD_KF

  ushort* po = split ? p1 : p0;
#pragma unroll
  for (int f = 0; f < 4; ++f) {
    psum[f] += __shfl_xor(psum[f], 16);
    psum[f] += __shfl_xor(psum[f], 32);
    for (int t = 0; t < 4; ++t) {
      ushort ok[4];
      for (int r = 0; r < 4; ++r) ok[r] = f2bf(oacc[f][t][r]);   // unnormalized
      ushort* dst = po + ((size_t)bh * L_ + qrow0 + f * 16 + col) * D_ + t * 16 + quad * 4;
      *(ushort4*)dst = make_ushort4(ok[0], ok[1], ok[2], ok[3]);
    }
    if (quad == 0)
      psumbuf[split * (16 * L_) + bh * L_ + qrow0 + f * 16 + col] = psum[f];
  }
}

// ---------------------------------------------------------------------------
// 3b) Combine: oat = (U0 + U1) / (P0 + P1), in-place over p0.
// ---------------------------------------------------------------------------
__global__ __launch_bounds__(256) void comb_kernel(ushort* __restrict__ p0,      // in/out (oat)
                                                   const ushort* __restrict__ p1,
                                                   const float* __restrict__ ps) {
  int idx = blockIdx.x * 256 + threadIdx.x;    // 1,048,576 = 16*4096*16
  int row = idx >> 4;                          // bh*4096 + qrow
  float inv = 1.0f / (ps[row] + ps[16 * L_ + row]);
  ushort4 a = ((const ushort4*)p0)[idx];
  ushort4 b = ((const ushort4*)p1)[idx];
  ((ushort4*)p0)[idx] = make_ushort4(
      f2bf((bf2f(a.x) + bf2f(b.x)) * inv),
      f2bf((bf2f(a.y) + bf2f(b.y)) * inv),
      f2bf((bf2f(a.z) + bf2f(b.z)) * inv),
      f2bf((bf2f(a.w) + bf2f(b.w)) * inv));
}

// ---------------------------------------------------------------------------
// 4) Proj GEMM + residual (MFMA), 2 ltiles x 2 octiles per wave.
//    x f32; OUT IS F32.
// ---------------------------------------------------------------------------
__global__ __launch_bounds__(256) void proj_kernel(const ushort* __restrict__ oin,
                                                   const ushort* __restrict__ pw,
                                                   const float* __restrict__ pb,
                                                   const float* __restrict__ x,
                                                   float* __restrict__ out) {
  int wid  = blockIdx.x * 4 + (threadIdx.x >> 6);   // 4096 waves
  int lane = threadIdx.x & 63;
  int quad = lane >> 4, col = lane & 15;
  int oct  = wid & 7;             // 32 oc
  int rest = wid >> 3;
  int lt   = rest & 127;          // 32 l
  int b    = rest >> 7;
  int l0 = lt * 32, oc0 = oct * 32;

  f32x4 acc[2][2];
  for (int i = 0; i < 2; ++i) for (int j = 0; j < 2; ++j)
    acc[i][j] = (f32x4){0.f, 0.f, 0.f, 0.f};

#pragma unroll
  for (int k0 = 0; k0 < C_; k0 += 32) {
    int hh = k0 >> 6, dk = k0 & 63;
    bf16x8 a[2], bb[2];
#pragma unroll
    for (int i = 0; i < 2; ++i)
      a[i] = *(const bf16x8*)(oin + ((size_t)(b * NH_ + hh) * L_ + l0 + i * 16 + col) * D_ + dk + quad * 8);
#pragma unroll
    for (int j = 0; j < 2; ++j)
      bb[j] = *(const bf16x8*)(pw + (size_t)(oc0 + j * 16 + col) * C_ + k0 + quad * 8);
#pragma unroll
    for (int i = 0; i < 2; ++i)
#pragma unroll
      for (int j = 0; j < 2; ++j)
        acc[i][j] = __builtin_amdgcn_mfma_f32_16x16x32_bf16(a[i], bb[j], acc[i][j], 0, 0, 0);
  }

#pragma unroll
  for (int j = 0; j < 2; ++j) {
    int oc = oc0 + j * 16 + col;
    float bias = pb[oc];
#pragma unroll
    for (int i = 0; i < 2; ++i) {
      int l = l0 + i * 16 + quad * 4;
      size_t off = ((size_t)b * C_ + oc) * L_ + l;
      float4 xv = *(const float4*)(x + off);
      float4 ov = make_float4(acc[i][j][0] + bias + xv.x,
                              acc[i][j][1] + bias + xv.y,
                              acc[i][j][2] + bias + xv.z,
                              acc[i][j][3] + bias + xv.w);
      *(float4*)(out + off) = ov;
    }
  }
}

// ---------------------------------------------------------------------------
extern "C" void kernel_launch(void* const* d_in, const int* in_sizes, int n_in,
                              void* d_out, int out_size, void* d_ws, size_t ws_size,
                              hipStream_t stream) {
  const float* x      = (const float*)d_in[0];
  const float* gn_w   = (const float*)d_in[1];
  const float* gn_b   = (const float*)d_in[2];
  const float* qkv_w  = (const float*)d_in[3];
  const float* qkv_b  = (const float*)d_in[4];
  const float* proj_w = (const float*)d_in[5];
  const float* proj_b = (const float*)d_in[6];
  float* out = (float*)d_out;     // OUTPUT IS F32

  const size_t TEN = (size_t)B_ * C_ * L_;   // 4,194,304 elements
  // ws: q | k | v | oat | wq | wp | stats (34.1 MB + 1 KB)
  // d_out (16.8 MB): [0,8.4M) hT bf16 (dead after qkv) -> psum f32 (512 KB);
  //                  [8.4M,16.8M) partial-1 (bf16).
  ushort* ws  = (ushort*)d_ws;
  ushort* q   = ws;                 // (B, nh, L, d) bf16 (pre-scaled)
  ushort* k   = ws + TEN;           // (B, nh, L, d) bf16
  ushort* v   = ws + 2 * TEN;       // (B, nh, d, L) bf16
  ushort* oat = ws + 3 * TEN;       // (B, nh, L, d) bf16 = partial-0, then O
  ushort* wq  = ws + 4 * TEN;       // (768,256) bf16
  ushort* wp  = wq + 768 * 256;     // (256,256) bf16
  float*  stats = (float*)(wp + 256 * 256);   // 256 f32 (zeroed by cvt)
  ushort* hT  = (ushort*)d_out;     // (B, L, C) bf16 staging inside d_out
  ushort* p1  = (ushort*)d_out + TEN;   // partial-1 (bf16)
  float*  psb = (float*)d_out;          // psum[2][16][4096] f32 over dead hT

  cvt_kernel <<<256,       256, 0, stream>>>(qkv_w, proj_w, wq, wp, stats);
  gn_stats   <<<1024,      256, 0, stream>>>(x, stats);
  gn_apply   <<<1024,      256, 0, stream>>>(x, gn_w, gn_b, stats, hT);
  qkv_kernel <<<6144 / 4,  256, 0, stream>>>(hT, wq, qkv_b, q, k, v);
  attn_kernel<<<512,       256, 0, stream>>>(q, k, v, oat, p1, psb);
  comb_kernel<<<4096,      256, 0, stream>>>(oat, p1, psb);
  proj_kernel<<<4096 / 4,  256, 0, stream>>>(oat, wp, proj_b, x, out);
}

// Round 8
// 211.034 us; speedup vs baseline: 2.1426x; 1.2169x over previous
//
#include <hip/hip_runtime.h>

// Problem constants
#define B_   4
#define C_   256
#define L_   4096     // H*W = 64*64
#define NH_  4
#define D_   64       // head dim
#define G_   32       // groups
#define CPG_ 8        // channels per group

typedef __bf16 bf16x8 __attribute__((ext_vector_type(8)));
typedef float  f32x4  __attribute__((ext_vector_type(4)));

__device__ __forceinline__ ushort f2bf(float f) {
  union { float f; unsigned u; } c; c.f = f;
  unsigned u = c.u;
  return (ushort)((u + 0x7fffu + ((u >> 16) & 1u)) >> 16);   // RNE, finite values only
}
__device__ __forceinline__ float bf2f(ushort h) {
  union { unsigned u; float f; } c; c.u = ((unsigned)h) << 16; return c.f;
}
__device__ __forceinline__ unsigned fbits(float f) {
  union { float f; unsigned u; } c; c.f = f; return c.u;
}
__device__ __forceinline__ float fastexp2(float x) {
#if __has_builtin(__builtin_amdgcn_exp2f)
  return __builtin_amdgcn_exp2f(x);
#else
  return exp2f(x);
#endif
}

// ---------------------------------------------------------------------------
// 0) pre_kernel = weight convert (f32->bf16) MERGED with GN stats.
//    blocks [0,1024): GN partial sums, DETERMINISTIC per-(bg,chunk) slots
//    (no atomics, no zero-init needed -> mergeable).  blocks [1024,1280): cvt.
// ---------------------------------------------------------------------------
__global__ __launch_bounds__(256) void pre_kernel(const float* __restrict__ x,
                                                  const float* __restrict__ wqf,
                                                  const float* __restrict__ wpf,
                                                  ushort* __restrict__ wq,
                                                  ushort* __restrict__ wp,
                                                  float* __restrict__ stats2) {
  int bidx = blockIdx.x;
  int tid  = threadIdx.x;
  if (bidx >= 1024) {
    int t = (bidx - 1024) * 256 + tid;        // 65536 threads, 4 elems each
    const int NQ4 = (768 * 256) / 4;          // 49152
    float4 v;
    if (t < NQ4) {
      v = ((const float4*)wqf)[t];
      ((ushort4*)wq)[t] = make_ushort4(f2bf(v.x), f2bf(v.y), f2bf(v.z), f2bf(v.w));
    } else {
      int i = t - NQ4;
      v = ((const float4*)wpf)[i];
      ((ushort4*)wp)[i] = make_ushort4(f2bf(v.x), f2bf(v.y), f2bf(v.z), f2bf(v.w));
    }
    return;
  }
  // GN stats part: bidx = bg*8 + chunk
  int bg = bidx >> 3, chunk = bidx & 7;
  int b = bg >> 5, g = bg & 31;
  const float* xg = x + ((size_t)b * C_ + g * CPG_) * L_ + chunk * 512;

  float s = 0.f, ss = 0.f;
  for (int c = 0; c < CPG_; ++c) {
    float2 v = ((const float2*)(xg + (size_t)c * L_))[tid];
    s  += v.x + v.y;
    ss += v.x * v.x + v.y * v.y;
  }
  for (int off = 32; off; off >>= 1) { s += __shfl_xor(s, off); ss += __shfl_xor(ss, off); }
  __shared__ float red[8];
  int w = tid >> 6;
  if ((tid & 63) == 0) { red[w] = s; red[4 + w] = ss; }
  __syncthreads();
  if (tid == 0) {
    stats2[bidx * 2]     = red[0] + red[1] + red[2] + red[3];
    stats2[bidx * 2 + 1] = red[4] + red[5] + red[6] + red[7];
  }
}

// ---------------------------------------------------------------------------
// 1b) GN apply: x (B,C,L) f32 -> hT (B,L,C) bf16, transposed.  1024 blocks.
//     Sums the 8 per-chunk partials (deterministic).
// ---------------------------------------------------------------------------
__global__ __launch_bounds__(256) void gn_apply(const float* __restrict__ x,
                                                const float* __restrict__ gw,
                                                const float* __restrict__ gb,
                                                const float* __restrict__ stats2,
                                                ushort* __restrict__ hT) {
  int bg = blockIdx.x >> 3, chunk = blockIdx.x & 7;
  int b = bg >> 5, g = bg & 31;
  const float* xg = x + ((size_t)b * C_ + g * CPG_) * L_;
  int tid = threadIdx.x;

  float s = 0.f, ss = 0.f;
#pragma unroll
  for (int c2 = 0; c2 < 8; ++c2) {
    s  += stats2[(bg * 8 + c2) * 2];
    ss += stats2[(bg * 8 + c2) * 2 + 1];
  }
  const float inv_n = 1.0f / (CPG_ * L_);
  float mean = s * inv_n;
  float var  = ss * inv_n - mean * mean;
  float rstd = rsqrtf(var + 1e-5f);

  float wv[CPG_], bv[CPG_];
  for (int c = 0; c < CPG_; ++c) { wv[c] = gw[g * CPG_ + c]; bv[c] = gb[g * CPG_ + c]; }

  for (int li = 0; li < 2; ++li) {
    int l = chunk * 512 + li * 256 + tid;
    union { ushort s[8]; uint4 u; } o;
    for (int c = 0; c < CPG_; ++c) {
      float v = xg[(size_t)c * L_ + l];
      o.s[c] = f2bf((v - mean) * rstd * wv[c] + bv[c]);
    }
    *(uint4*)(hT + ((size_t)b * L_ + l) * C_ + g * CPG_) = o.u;
  }
}

// ---------------------------------------------------------------------------
// 2) QKV GEMM (MFMA), 4 otiles x 2 ltiles per wave (64 o x 32 l).
//    q,k (b,h,L,d); v (b,h,d,L).  q PRE-SCALED by 0.125*log2(e).
// ---------------------------------------------------------------------------
__global__ __launch_bounds__(256) void qkv_kernel(const ushort* __restrict__ hT,
                                                  const ushort* __restrict__ w,
                                                  const float* __restrict__ bias,
                                                  ushort* __restrict__ q,
                                                  ushort* __restrict__ k,
                                                  ushort* __restrict__ v) {
  int wid  = blockIdx.x * 4 + (threadIdx.x >> 6);   // 6144 waves
  int lane = threadIdx.x & 63;
  int quad = lane >> 4, col = lane & 15;
  int ot   = wid % 12;            // 64 o-channels
  int rest = wid / 12;
  int lt   = rest & 127;          // 32 l
  int b    = rest >> 7;
  int o0 = ot * 64, l0 = lt * 32;

  const ushort* abase = w  + (size_t)(o0 + col) * C_ + quad * 8;
  const ushort* bbase = hT + ((size_t)b * L_ + l0 + col) * C_ + quad * 8;

  f32x4 acc[4][2];
  for (int i = 0; i < 4; ++i) for (int j = 0; j < 2; ++j)
    acc[i][j] = (f32x4){0.f, 0.f, 0.f, 0.f};

#pragma unroll
  for (int k0 = 0; k0 < C_; k0 += 32) {
    bf16x8 a[4], bb[2];
#pragma unroll
    for (int i = 0; i < 4; ++i) a[i]  = *(const bf16x8*)(abase + (size_t)(i * 16) * C_ + k0);
#pragma unroll
    for (int j = 0; j < 2; ++j) bb[j] = *(const bf16x8*)(bbase + (size_t)(j * 16) * C_ + k0);
#pragma unroll
    for (int i = 0; i < 4; ++i)
#pragma unroll
      for (int j = 0; j < 2; ++j)
        acc[i][j] = __builtin_amdgcn_mfma_f32_16x16x32_bf16(a[i], bb[j], acc[i][j], 0, 0, 0);
  }

  int third = o0 >> 8;                       // wave-uniform (o0 is 64-aligned)
  int hh    = (o0 & 255) >> 6;               // wave-uniform
  float scale = (third == 0) ? 0.180336880111120f : 1.0f;  // 0.125*log2(e) on q
#pragma unroll
  for (int i = 0; i < 4; ++i) {
    int oo = o0 + i * 16 + quad * 4;
    int dd = i * 16 + quad * 4;
#pragma unroll
    for (int j = 0; j < 2; ++j) {
      int l = l0 + j * 16 + col;
      ushort pk[4];
      for (int r = 0; r < 4; ++r) pk[r] = f2bf((acc[i][j][r] + bias[oo + r]) * scale);
      if (third < 2) {
        ushort* dst = (third ? k : q) + (((size_t)(b * NH_ + hh) * L_ + l) * D_ + dd);
        *(ushort4*)dst = make_ushort4(pk[0], pk[1], pk[2], pk[3]);
      } else {
        for (int r = 0; r < 4; ++r)
          v[((size_t)(b * NH_ + hh) * D_ + dd + r) * L_ + l] = pk[r];
      }
    }
  }
}

// ---------------------------------------------------------------------------
// 3) Flash attention (MFMA) v13 = v7 (R4 best, 77.5us) + MFMA-psum:
//    the 64 VALU psum adds/tile/wave (~40% of VALU pipe) move to the
//    61%-idle MFMA pipe via pacc[f] = mfma(ones, pb[f], pacc[f]) (row-sum;
//    permutation-invariant; numerically verified in R1).  Also deletes the
//    end shuffle-reduce (pacc[f][0] at quad 0 IS the row sum).
//    Everything else identical to v7: 64 q-rows/wave, split=2, grid 512,
//    256 thr, __launch_bounds__(256,2), V via LDS dbuf + kpos permutation,
//    K via LDS dbuf, one barrier/tile, reg-staged prefetch.
//    Spill guard: WRITE_SIZE must stay ~16.9MB (R3/R7 lesson).
// ---------------------------------------------------------------------------
__global__ __launch_bounds__(256, 2) void attn_kernel(const ushort* __restrict__ q,
                                                      const ushort* __restrict__ k,
                                                      const ushort* __restrict__ v,
                                                      ushort* __restrict__ p0,
                                                      ushort* __restrict__ p1,
                                                      float* __restrict__ psumbuf) {
  __shared__ __align__(16) ushort k_lds[2][64][72];   // K tiles, +8 pad
  __shared__ __align__(16) ushort v_lds[2][64][72];   // V^T tiles (permuted), +8 pad

  int tid   = threadIdx.x;
  int w     = tid >> 6, lane = tid & 63;
  int quad  = lane >> 4, col = lane & 15;
  int bid   = (int)blockIdx.x;
  bid = (bid & 7) * 64 + (bid >> 3);     // XCD-contiguous work ids (512 % 8 == 0)
  int split = bid >> 8;                  // 0 or 1
  int bh    = (bid >> 4) & 15;
  int qblk  = bid & 15;

  const ushort* qp = q + (size_t)bh * L_ * D_;
  const ushort* kp = k + (size_t)bh * L_ * D_;
  const ushort* vp = v + (size_t)bh * D_ * L_;

  int qrow0 = qblk * 256 + w * 64;       // this wave's 64 q-rows
  bf16x8 bq[4][2];                       // [frag][c]
#pragma unroll
  for (int f = 0; f < 4; ++f)
#pragma unroll
    for (int c = 0; c < 2; ++c)
      bq[f][c] = *(const bf16x8*)(qp + (size_t)(qrow0 + f * 16 + col) * D_ + c * 32 + quad * 8);

  f32x4 oacc[4][4];
#pragma unroll
  for (int f = 0; f < 4; ++f)
    for (int t = 0; t < 4; ++t) oacc[f][t] = (f32x4){0.f, 0.f, 0.f, 0.f};
  f32x4 pacc[4];
#pragma unroll
  for (int f = 0; f < 4; ++f) pacc[f] = (f32x4){0.f, 0.f, 0.f, 0.f};
  const f32x4 Z = (f32x4){0.f, 0.f, 0.f, 0.f};

  union { ushort s[8]; bf16x8 v8; } one_u;
#pragma unroll
  for (int i = 0; i < 8; ++i) one_u.s[i] = 0x3F80;    // bf16 1.0
  bf16x8 ones = one_u.v8;

  int vrow = tid >> 2, vchunk = tid & 3;
  int vwoff = (vchunk >> 1) * 32 + (vchunk & 1) * 4;   // permuted V store base
  int kt0 = split * (L_ / 2), kt_end = kt0 + L_ / 2;

  // prologue: stage tile kt0 into buffer 0 (V permuted)
  {
    const uint4* ksrc = (const uint4*)(kp + (size_t)kt0 * D_);   // 8 KB contiguous
    uint4 a  = ksrc[tid];
    uint4 b2 = ksrc[tid + 256];
    const uint4* vsrc = (const uint4*)(vp + (size_t)vrow * L_ + kt0);
    uint4 c0 = vsrc[vchunk * 2];
    uint4 c1 = vsrc[vchunk * 2 + 1];
    *(uint4*)&k_lds[0][tid >> 3][(tid & 7) * 8] = a;
    *(uint4*)&k_lds[0][32 + (tid >> 3)][(tid & 7) * 8] = b2;
    ushort* vb = &v_lds[0][vrow][vwoff];
    *(uint2*)(vb + 0)  = make_uint2(c0.x, c0.y);
    *(uint2*)(vb + 8)  = make_uint2(c0.z, c0.w);
    *(uint2*)(vb + 16) = make_uint2(c1.x, c1.y);
    *(uint2*)(vb + 24) = make_uint2(c1.z, c1.w);
  }
  __syncthreads();

  int cur = 0;
  for (int kt = kt0; kt < kt_end; kt += 64) {
    bool has_next = (kt + 64) < kt_end;   // block-uniform

    // ---- Phase 1: QK^T for BOTH 32-kpos halves (32 indep MFMAs) ----
    f32x4 s[2][4][2];   // [h][f][{rows col, rows 16+col}]
#pragma unroll
    for (int h = 0; h < 2; ++h) {
      bf16x8 a00 = *(const bf16x8*)&k_lds[cur][h * 32 + col][quad * 8];
      bf16x8 a01 = *(const bf16x8*)&k_lds[cur][h * 32 + col][32 + quad * 8];
      bf16x8 a10 = *(const bf16x8*)&k_lds[cur][h * 32 + 16 + col][quad * 8];
      bf16x8 a11 = *(const bf16x8*)&k_lds[cur][h * 32 + 16 + col][32 + quad * 8];
#pragma unroll
      for (int f = 0; f < 4; ++f) {
        s[h][f][0] = __builtin_amdgcn_mfma_f32_16x16x32_bf16(a00, bq[f][0], Z, 0, 0, 0);
        s[h][f][1] = __builtin_amdgcn_mfma_f32_16x16x32_bf16(a10, bq[f][0], Z, 0, 0, 0);
        s[h][f][0] = __builtin_amdgcn_mfma_f32_16x16x32_bf16(a01, bq[f][1], s[h][f][0], 0, 0, 0);
        s[h][f][1] = __builtin_amdgcn_mfma_f32_16x16x32_bf16(a11, bq[f][1], s[h][f][1], 0, 0, 0);
      }
    }

    // ---- Phase 2: issue next tile's global loads (land under exp/PV) ----
    uint4 nk0, nk1, nv0, nv1;
    if (has_next) {
      const uint4* ksrc = (const uint4*)(kp + (size_t)(kt + 64) * D_);
      nk0 = ksrc[tid];
      nk1 = ksrc[tid + 256];
      const uint4* vsrc = (const uint4*)(vp + (size_t)vrow * L_ + (kt + 64));
      nv0 = vsrc[vchunk * 2];
      nv1 = vsrc[vchunk * 2 + 1];
    }

    // ---- Phase 3: per half: exp/pack (VALU) + psum (MFMA) + PV (MFMA) ----
#pragma unroll
    for (int h = 0; h < 2; ++h) {
      bf16x8 pb[4];
#pragma unroll
      for (int f = 0; f < 4; ++f) {
        float pe0[4], pe1[4];
#pragma unroll
        for (int r = 0; r < 4; ++r) {
          pe0[r] = fastexp2(s[h][f][0][r]);
          pe1[r] = fastexp2(s[h][f][1][r]);
        }
        // B-frag IS our own values under the kpos permutation.
        union { unsigned u[4]; bf16x8 v8; } pc;
        pc.u[0] = __builtin_amdgcn_perm(fbits(pe0[1]), fbits(pe0[0]), 0x07060302u);
        pc.u[1] = __builtin_amdgcn_perm(fbits(pe0[3]), fbits(pe0[2]), 0x07060302u);
        pc.u[2] = __builtin_amdgcn_perm(fbits(pe1[1]), fbits(pe1[0]), 0x07060302u);
        pc.u[3] = __builtin_amdgcn_perm(fbits(pe1[3]), fbits(pe1[2]), 0x07060302u);
        pb[f] = pc.v8;
      }
      // psum on the matrix pipe: row-sum of P (permutation-invariant)
#pragma unroll
      for (int f = 0; f < 4; ++f)
        pacc[f] = __builtin_amdgcn_mfma_f32_16x16x32_bf16(ones, pb[f], pacc[f], 0, 0, 0);
#pragma unroll
      for (int t = 0; t < 4; ++t) {
        // ONE b128 read feeds FOUR MFMAs (V pre-permuted at store time)
        bf16x8 av = *(const bf16x8*)&v_lds[cur][t * 16 + col][h * 32 + quad * 8];
#pragma unroll
        for (int f = 0; f < 4; ++f)
          oacc[f][t] = __builtin_amdgcn_mfma_f32_16x16x32_bf16(av, pb[f], oacc[f][t], 0, 0, 0);
      }
    }

    if (has_next) {
      int nb = cur ^ 1;
      *(uint4*)&k_lds[nb][tid >> 3][(tid & 7) * 8] = nk0;
      *(uint4*)&k_lds[nb][32 + (tid >> 3)][(tid & 7) * 8] = nk1;
      ushort* vb = &v_lds[nb][vrow][vwoff];
      *(uint2*)(vb + 0)  = make_uint2(nv0.x, nv0.y);
      *(uint2*)(vb + 8)  = make_uint2(nv0.z, nv0.w);
      *(uint2*)(vb + 16) = make_uint2(nv1.x, nv1.y);
      *(uint2*)(vb + 24) = make_uint2(nv1.z, nv1.w);
      __syncthreads();
      cur = nb;
    }
  }

  ushort* po = split ? p1 : p0;
#pragma unroll
  for (int f = 0; f < 4; ++f) {
    for (int t = 0; t < 4; ++t) {
      ushort ok[4];
      for (int r = 0; r < 4; ++r) ok[r] = f2bf(oacc[f][t][r]);   // unnormalized
      ushort* dst = po + ((size_t)bh * L_ + qrow0 + f * 16 + col) * D_ + t * 16 + quad * 4;
      *(ushort4*)dst = make_ushort4(ok[0], ok[1], ok[2], ok[3]);
    }
    if (quad == 0)
      psumbuf[split * (16 * L_) + bh * L_ + qrow0 + f * 16 + col] = pacc[f][0];
  }
}

// ---------------------------------------------------------------------------
// 3b) Combine: oat = (U0 + U1) / (P0 + P1), in-place over p0.  uint4/thread.
// ---------------------------------------------------------------------------
__global__ __launch_bounds__(256) void comb_kernel(ushort* __restrict__ p0,      // in/out (oat)
                                                   const ushort* __restrict__ p1,
                                                   const float* __restrict__ ps) {
  int idx = blockIdx.x * 256 + threadIdx.x;    // 524,288 uint4s = 16*4096*64 bf16
  int row = idx >> 3;                          // bh*4096 + qrow (8 elems/row-chunk)
  float inv = 1.0f / (ps[row] + ps[16 * L_ + row]);
  union { uint4 u; ushort s[8]; } ua, ub, o;
  ua.u = ((const uint4*)p0)[idx];
  ub.u = ((const uint4*)p1)[idx];
#pragma unroll
  for (int e = 0; e < 8; ++e)
    o.s[e] = f2bf((bf2f(ua.s[e]) + bf2f(ub.s[e])) * inv);
  ((uint4*)p0)[idx] = o.u;
}

// ---------------------------------------------------------------------------
// 4) Proj GEMM + residual (MFMA), 2 ltiles x 2 octiles per wave.
//    x f32; OUT IS F32.
// ---------------------------------------------------------------------------
__global__ __launch_bounds__(256) void proj_kernel(const ushort* __restrict__ oin,
                                                   const ushort* __restrict__ pw,
                                                   const float* __restrict__ pb,
                                                   const float* __restrict__ x,
                                                   float* __restrict__ out) {
  int wid  = blockIdx.x * 4 + (threadIdx.x >> 6);   // 4096 waves
  int lane = threadIdx.x & 63;
  int quad = lane >> 4, col = lane & 15;
  int oct  = wid & 7;             // 32 oc
  int rest = wid >> 3;
  int lt   = rest & 127;          // 32 l
  int b    = rest >> 7;
  int l0 = lt * 32, oc0 = oct * 32;

  f32x4 acc[2][2];
  for (int i = 0; i < 2; ++i) for (int j = 0; j < 2; ++j)
    acc[i][j] = (f32x4){0.f, 0.f, 0.f, 0.f};

#pragma unroll
  for (int k0 = 0; k0 < C_; k0 += 32) {
    int hh = k0 >> 6, dk = k0 & 63;
    bf16x8 a[2], bb[2];
#pragma unroll
    for (int i = 0; i < 2; ++i)
      a[i] = *(const bf16x8*)(oin + ((size_t)(b * NH_ + hh) * L_ + l0 + i * 16 + col) * D_ + dk + quad * 8);
#pragma unroll
    for (int j = 0; j < 2; ++j)
      bb[j] = *(const bf16x8*)(pw + (size_t)(oc0 + j * 16 + col) * C_ + k0 + quad * 8);
#pragma unroll
    for (int i = 0; i < 2; ++i)
#pragma unroll
      for (int j = 0; j < 2; ++j)
        acc[i][j] = __builtin_amdgcn_mfma_f32_16x16x32_bf16(a[i], bb[j], acc[i][j], 0, 0, 0);
  }

#pragma unroll
  for (int j = 0; j < 2; ++j) {
    int oc = oc0 + j * 16 + col;
    float bias = pb[oc];
#pragma unroll
    for (int i = 0; i < 2; ++i) {
      int l = l0 + i * 16 + quad * 4;
      size_t off = ((size_t)b * C_ + oc) * L_ + l;
      float4 xv = *(const float4*)(x + off);
      float4 ov = make_float4(acc[i][j][0] + bias + xv.x,
                              acc[i][j][1] + bias + xv.y,
                              acc[i][j][2] + bias + xv.z,
                              acc[i][j][3] + bias + xv.w);
      *(float4*)(out + off) = ov;
    }
  }
}

// ---------------------------------------------------------------------------
extern "C" void kernel_launch(void* const* d_in, const int* in_sizes, int n_in,
                              void* d_out, int out_size, void* d_ws, size_t ws_size,
                              hipStream_t stream) {
  const float* x      = (const float*)d_in[0];
  const float* gn_w   = (const float*)d_in[1];
  const float* gn_b   = (const float*)d_in[2];
  const float* qkv_w  = (const float*)d_in[3];
  const float* qkv_b  = (const float*)d_in[4];
  const float* proj_w = (const float*)d_in[5];
  const float* proj_b = (const float*)d_in[6];
  float* out = (float*)d_out;     // OUTPUT IS F32

  const size_t TEN = (size_t)B_ * C_ * L_;   // 4,194,304 elements
  // ws: q | k | v | oat | wq | wp  (34.1 MB)
  // d_out (16.8 MB): [0,8.4M) hT bf16 (dead after qkv) -> psum f32 (512 KB);
  //                  [8.4M,16.8M) stats2 f32 8KB (dead after gn_apply) ->
  //                               partial-1 (bf16).
  ushort* ws  = (ushort*)d_ws;
  ushort* q   = ws;                 // (B, nh, L, d) bf16 (pre-scaled)
  ushort* k   = ws + TEN;           // (B, nh, L, d) bf16
  ushort* v   = ws + 2 * TEN;       // (B, nh, d, L) bf16
  ushort* oat = ws + 3 * TEN;       // (B, nh, L, d) bf16 = partial-0, then O
  ushort* wq  = ws + 4 * TEN;       // (768,256) bf16
  ushort* wp  = wq + 768 * 256;     // (256,256) bf16
  ushort* hT  = (ushort*)d_out;     // (B, L, C) bf16 staging inside d_out
  ushort* p1  = (ushort*)d_out + TEN;   // partial-1 (bf16)
  float*  st2 = (float*)((ushort*)d_out + TEN);  // 2048 f32 GN partials (pre-attn)
  float*  psb = (float*)d_out;          // psum[2][16][4096] f32 over dead hT

  pre_kernel <<<1280,      256, 0, stream>>>(x, qkv_w, proj_w, wq, wp, st2);
  gn_apply   <<<1024,      256, 0, stream>>>(x, gn_w, gn_b, st2, hT);
  qkv_kernel <<<6144 / 4,  256, 0, stream>>>(hT, wq, qkv_b, q, k, v);
  attn_kernel<<<512,       256, 0, stream>>>(q, k, v, oat, p1, psb);
  comb_kernel<<<2048,      256, 0, stream>>>(oat, p1, psb);
  proj_kernel<<<4096 / 4,  256, 0, stream>>>(oat, wp, proj_b, x, out);
}